// Round 4
// baseline (267.248 us; speedup 1.0000x reference)
//
#include <hip/hip_runtime.h>

// Problem: img [B=256, C=3, H=224, W=224] f32; zero a 32x32 square per batch
// (all channels), copy the rest. ~308 MB traffic -> ~49 us floor @6.3 TB/s.
//
// Rounds 1-2: hipcc sinks batched loads into the store loop regardless of
// sched_barrier(0) (VGPR 24->20 proved it) -> load->vmcnt(0)->store chain,
// 2.5-3.3 TB/s at 63% occupancy, while write-only fills hit 6.7 TB/s at 9.6%.
// Round 3: D2D-blit + zero-squares approach FAILED only because out_size is
// an ELEMENT count, not bytes (copied 38.5 of 154 MB). Fixed here: *4.
//
//   1. hipMemcpyAsync D2D (graph-capture-legal per Guideline 9) does the
//      154 MB copy on AMD's tuned blit path (~6.3 TB/s ubench ceiling).
//   2. zero_squares: write-only kernel touching 3.1 MB (256*3*32*32 floats),
//      zero reads of img. Stream ordering puts it after the copy.

#define SQ 32
#define B_ 256
#define C_ 3
#define H_ 224
#define W_ 224

__global__ __launch_bounds__(256) void zero_squares(float* __restrict__ out,
                                                    const int* __restrict__ y_idx,
                                                    const int* __restrict__ x_idx) {
    const int b  = (int)blockIdx.x;        // one block per batch
    const int y0 = y_idx[b];               // uniform -> s_load
    const int x0 = x_idx[b];               // uniform -> s_load
    const int t  = (int)threadIdx.x;

    // 3 ch * 32 rows * 32 cols = 3072 elements per batch; 256 threads -> 12 each.
    // Each 32-lane group covers one contiguous 128 B row segment.
#pragma unroll
    for (int e = t; e < C_ * SQ * SQ; e += 256) {
        const int c = e >> 10;             // /1024: channel
        const int r = (e >> 5) & 31;       // row within square
        const int x = e & 31;              // col within square
        out[((b * C_ + c) * H_ + (y0 + r)) * W_ + (x0 + x)] = 0.0f;
    }
}

extern "C" void kernel_launch(void* const* d_in, const int* in_sizes, int n_in,
                              void* d_out, int out_size, void* d_ws, size_t ws_size,
                              hipStream_t stream) {
    const void* img  = d_in[0];
    const int*  yidx = (const int*)d_in[1];
    const int*  xidx = (const int*)d_in[2];

    // out_size is the ELEMENT count (38,535,168 floats) -> bytes = *4.
    const size_t nbytes = (size_t)out_size * sizeof(float);

    // 1) Bulk copy img -> out on the runtime's tuned D2D path.
    hipMemcpyAsync(d_out, img, nbytes, hipMemcpyDeviceToDevice, stream);

    // 2) Zero the 32x32 squares (3.1 MB of writes, no reads of img).
    zero_squares<<<dim3(B_), 256, 0, stream>>>((float*)d_out, yidx, xidx);
}

// Round 5
// 264.807 us; speedup vs baseline: 1.0092x; 1.0092x over previous
//
#include <hip/hip_runtime.h>

// Problem: img [B=256, C=3, H=224, W=224] f32; zero a 32x32 square per batch
// (all channels), copy the rest. ~308 MB traffic -> ~49 us floor @6.3 TB/s.
//
// History: every structure so far lands 86-97 us (~3.4 TB/s) regardless of
// HBM bytes (round 2: 75 MB vs 154 MB fetched, same time; VALUBusy 3%):
//  - r0: 1 float4/thread one-shot           ~86 us
//  - r1/r2: 7 f4/thread, loads SUNK by hipcc (VGPR 20!) -> MLP=1, 92-93 us
//    (sched_barrier(0) does NOT stop the IR-level sink)
//  - r4: hipMemcpyAsync went to SDMA, ~97 us
// Diagnosis: per-wave load->vmcnt(0)->store serialization. m13 proves 6.29
// TB/s float4 copy is achievable -> need real MLP.
//
// This version forces MLP=7 with ONE volatile asm block: 7x
// global_load_dwordx4 issued back-to-back + s_waitcnt vmcnt(0) inside the
// asm. Opaque to the scheduler: the batch cannot be sunk. Mask+store stay in
// C, data-dependent on the asm outputs. Plain stores (fills: 6.5 TB/s).

#define SQ 32
#define B_ 256
#define C_ 3
#define H_ 224
#define W_ 224

#define W4 (W_ / 4)               // 56 float4 per row
#define PLANE4 (H_ * W4)          // 12544 float4 per (b,c) plane
#define SPLIT 7                   // chunks per plane
#define CHUNK4 (PLANE4 / SPLIT)   // 1792 float4 per chunk
#define TPB 256
#define ITERS (CHUNK4 / TPB)      // 7 float4 per thread, exact

typedef float v4f __attribute__((ext_vector_type(4)));

__global__ __launch_bounds__(TPB) void rsd_kernel(const v4f* __restrict__ img,
                                                  const int* __restrict__ y_idx,
                                                  const int* __restrict__ x_idx,
                                                  v4f* __restrict__ out) {
    const int blk   = (int)blockIdx.x;
    const int plane = blk / SPLIT;           // uniform (b*C + c)
    const int chunk = blk - plane * SPLIT;   // uniform
    const int b     = plane / C_;            // uniform

    const int y0 = y_idx[b];                 // uniform -> s_load
    const int x0 = x_idx[b];                 // uniform -> s_load

    const int t     = (int)threadIdx.x;
    const int base4 = plane * PLANE4 + chunk * CHUNK4 + t;

    const v4f* p = img + base4;

    // 7 loads in flight per thread, drained once. Opaque asm: hipcc cannot
    // sink these into the store loop (rounds 1-2 failure mode).
    v4f v0, v1, v2, v3, v4, v5, v6;
    asm volatile(
        "global_load_dwordx4 %0, %[a0], off\n\t"
        "global_load_dwordx4 %1, %[a1], off\n\t"
        "global_load_dwordx4 %2, %[a2], off\n\t"
        "global_load_dwordx4 %3, %[a3], off\n\t"
        "global_load_dwordx4 %4, %[a4], off\n\t"
        "global_load_dwordx4 %5, %[a5], off\n\t"
        "global_load_dwordx4 %6, %[a6], off\n\t"
        "s_waitcnt vmcnt(0)"
        : "=&v"(v0), "=&v"(v1), "=&v"(v2), "=&v"(v3),
          "=&v"(v4), "=&v"(v5), "=&v"(v6)
        : [a0] "v"(p),           [a1] "v"(p + 1 * TPB), [a2] "v"(p + 2 * TPB),
          [a3] "v"(p + 3 * TPB), [a4] "v"(p + 4 * TPB), [a5] "v"(p + 5 * TPB),
          [a6] "v"(p + 6 * TPB));

    const int o4b = chunk * CHUNK4 + t;

    // Mask (verified correct in rounds 1-2) + plain store.
#define MASK_STORE(K, V)                                     \
    {                                                        \
        const int o4 = o4b + (K) * TPB;                      \
        const int h  = o4 / W4;          /* magic-mul */     \
        const int w  = (o4 - h * W4) << 2;                   \
        const int cx = w - x0;                               \
        if ((unsigned)(h - y0) < SQ) {                       \
            if ((unsigned)(cx + 0) < SQ) V.x = 0.0f;         \
            if ((unsigned)(cx + 1) < SQ) V.y = 0.0f;         \
            if ((unsigned)(cx + 2) < SQ) V.z = 0.0f;         \
            if ((unsigned)(cx + 3) < SQ) V.w = 0.0f;         \
        }                                                    \
        out[base4 + (K) * TPB] = V;                          \
    }

    MASK_STORE(0, v0)
    MASK_STORE(1, v1)
    MASK_STORE(2, v2)
    MASK_STORE(3, v3)
    MASK_STORE(4, v4)
    MASK_STORE(5, v5)
    MASK_STORE(6, v6)
#undef MASK_STORE
}

extern "C" void kernel_launch(void* const* d_in, const int* in_sizes, int n_in,
                              void* d_out, int out_size, void* d_ws, size_t ws_size,
                              hipStream_t stream) {
    const v4f* img  = (const v4f*)d_in[0];
    const int* yidx = (const int*)d_in[1];
    const int* xidx = (const int*)d_in[2];
    v4f*       out  = (v4f*)d_out;

    // 256 * 3 * 7 = 5376 blocks x 256 threads x 7 float4 = 9,633,792 float4
    // = exactly out_size/4 float4. No tail.
    rsd_kernel<<<dim3(B_ * C_ * SPLIT), TPB, 0, stream>>>(img, yidx, xidx, out);
}